// Round 13
// baseline (356.873 us; speedup 1.0000x reference)
//
#include <hip/hip_runtime.h>
#include <hip/hip_bf16.h>

// EditModel: bidi prior LSTM (H=256) + modern LSTM (H=512) + factored
// logit heads. ctx@W^T = prior@W^T (+) modern@W^T so no [P,M,B,2H] tensor.
//
// R13: ZERO inter-block synchronization. The LSTM time loop is 32 separate
// kernel launches (graph-captured, ~2-3us/node on replay); kernel boundaries
// provide all ordering/coherence. No flags, no polls, no spin, no sc0, no
// co-residency assumptions -- deadlock structurally impossible. Six straight
// timeouts (incl. R11 = previously-passing R6 verbatim, and R12 = static
// 64-WG assignment) implicate the persistent-kernel spin protocol / wedged
// pod; this removes the entire axis. Data path keeps every proven win:
// fragment-tiled h (1KB contiguous A bursts + vmcnt quarters), LDS-B in
// fragment order, wihT bias-folded coalesced input-projection gather.
// Cell state c round-trips a 512KB global buffer (aliased into SMi scratch).

#define PLEN 32
#define MLEN 32
#define BATCH 128
#define HP 256
#define HMOD 512
#define DIN 54
#define OUTV 53

typedef __bf16 bf16x8 __attribute__((ext_vector_type(8)));
typedef float f32x4 __attribute__((ext_vector_type(4)));
typedef int i32x4 __attribute__((ext_vector_type(4)));

// ---- workspace layout (bytes) ----
#define WS_SRCIDX   1024
#define WS_WHH_PF   17408
#define WS_WHH_PB   541696
#define WS_WHH_M    1065984
#define WS_WSUB     3163136
#define WS_WINS     3228672
#define WS_HF       3294208
#define WS_HB       5391360
#define WS_HM       7488512
#define WS_SPS      11682816   // 4096*64 f32
#define WS_SPI      12731392
#define WS_SMS      13779968
#define WS_SMI      14828544   // ends 15877120 (same footprint as R6)
// Aliases (regions dead during the LSTM phase):
#define WS_WIHT_M   WS_SPS     // 54*2048 f32 = 442368 B
#define WS_WIHT_PF  WS_SPI     // 54*1024 f32
#define WS_WIHT_PB  WS_SMS     // 54*1024 f32
#define WS_CST      WS_SMI     // 64*256*8 f32 = 524288 B <= 1MB region

#define OFF_END 131072
#define OFF_SUB 262144
#define OFF_INS 389120

__device__ __forceinline__ float sigf(float x) { return 1.0f / (1.0f + __expf(-x)); }
__device__ __forceinline__ float tanhfast(float x) {
  x = fminf(15.0f, fmaxf(-15.0f, x));
  float e = __expf(2.0f * x);
  return (e - 1.0f) / (e + 1.0f);
}

__device__ __forceinline__ i32x4 load_g16(const void* p) {
  i32x4 r;
  asm volatile("global_load_dwordx4 %0, %1, off" : "=v"(r) : "v"(p) : "memory");
  return r;
}

#define VMWAIT(n) do { asm volatile("s_waitcnt vmcnt(" #n ")" ::: "memory"); \
                       __builtin_amdgcn_sched_barrier(0); } while (0)

__global__ void prep_kernel(const float* __restrict__ Whh_pf, const float* __restrict__ Whh_pb,
                            const float* __restrict__ Whh_m,
                            const float* __restrict__ W_sub, const float* __restrict__ W_ins,
                            const float* __restrict__ src_oh,
                            const float* __restrict__ Wih_pf, const float* __restrict__ b_pf,
                            const float* __restrict__ Wih_pb, const float* __restrict__ b_pb,
                            const float* __restrict__ Wih_m,  const float* __restrict__ b_m,
                            __hip_bfloat16* __restrict__ whh_pf_b, __hip_bfloat16* __restrict__ whh_pb_b,
                            __hip_bfloat16* __restrict__ whh_m_b,
                            __hip_bfloat16* __restrict__ wsub_b, __hip_bfloat16* __restrict__ wins_b,
                            float* __restrict__ wihT_m, float* __restrict__ wihT_pf,
                            float* __restrict__ wihT_pb,
                            int* __restrict__ src_idx)
{
  int tid = blockIdx.x * blockDim.x + threadIdx.x;
  int stride = gridDim.x * blockDim.x;
  for (int k = tid; k < 4 * HP * HP; k += stride) {
    whh_pf_b[k] = __float2bfloat16(Whh_pf[k]);
    whh_pb_b[k] = __float2bfloat16(Whh_pb[k]);
  }
  for (int k = tid; k < 4 * HMOD * HMOD; k += stride)
    whh_m_b[k] = __float2bfloat16(Whh_m[k]);
  for (int k = tid; k < 64 * HMOD; k += stride) {
    int r = k >> 9, c = k & 511;
    wsub_b[k] = __float2bfloat16(r < OUTV ? W_sub[r * HMOD + c] : 0.0f);
    wins_b[k] = __float2bfloat16(r < OUTV ? W_ins[r * HMOD + c] : 0.0f);
  }
  // transposed input-proj weights, bias folded: wihT[ii][c] = Wih[c][ii]+b[c]
  for (int j = tid; j < DIN * 4 * HMOD; j += stride) {
    int ii = j >> 11, c = j & 2047;
    wihT_m[j] = Wih_m[(size_t)c * DIN + ii] + b_m[c];
  }
  for (int j = tid; j < DIN * 4 * HP; j += stride) {
    int ii = j >> 10, c = j & 1023;
    wihT_pf[j] = Wih_pf[(size_t)c * DIN + ii] + b_pf[c];
    wihT_pb[j] = Wih_pb[(size_t)c * DIN + ii] + b_pb[c];
  }
  for (int k = tid; k < PLEN * BATCH; k += stride) {
    const float* row = src_oh + (size_t)k * DIN;
    int idx = 0;
    for (int j = 0; j < DIN; ++j) if (row[j] > 0.5f) idx = j;
    src_idx[k] = idx;
  }
}

// h history layout, per LSTM (NK = H/32 k-blocks):
//   tile(t, btile, kk) = 512 bf16 (1KB) at ((t*8 + btile)*NK + kk)*512
//   elem within tile: (m*4 + kgc)*8 + j, m = b&15, k = kk*32 + kgc*8 + j.
// A wave's MFMA A-fragment load covers one full tile contiguously.

#define DO_QUARTER(Q0)                                                          \
  _Pragma("unroll")                                                             \
  for (int kk2 = 0; kk2 < NK / 4; ++kk2) {                                      \
    bf16x8 a0 = __builtin_bit_cast(bf16x8, a[0][(Q0) + kk2]);                   \
    bf16x8 a1 = __builtin_bit_cast(bf16x8, a[1][(Q0) + kk2]);                   \
    _Pragma("unroll")                                                           \
    for (int g = 0; g < 4; ++g) {                                               \
      bf16x8 bfr = *reinterpret_cast<const bf16x8*>(                            \
          ldsB + ((((Q0) + kk2) * 4 + g) * 64 + lane) * 16);                    \
      acc[0][g] = __builtin_amdgcn_mfma_f32_16x16x32_bf16(a0, bfr, acc[0][g], 0, 0, 0); \
      acc[1][g] = __builtin_amdgcn_mfma_f32_16x16x32_bf16(a1, bfr, acc[1][g], 0, 0, 0); \
    }                                                                           \
  }

// Coalesced-friendly gather: within a kg-group ii is uniform and col is
// consecutive -> 4 cache lines per instruction.
#define LOAD_WIN(dst, tt)                                                       \
  do {                                                                          \
    int tin_ = REV ? (31 - (tt)) : (tt);                                        \
    _Pragma("unroll")                                                           \
    for (int bt = 0; bt < 2; ++bt) {                                            \
      _Pragma("unroll")                                                         \
      for (int r = 0; r < 4; ++r) {                                             \
        int b_ = (bt0 + bt) * 16 + kg * 4 + r;                                  \
        int ii_ = idx[tin_ * BATCH + b_];                                       \
        const float* row_ = wihT + (size_t)ii_ * (4 * H);                       \
        _Pragma("unroll")                                                       \
        for (int g = 0; g < 4; ++g) dst[bt][r][g] = row_[g * H + col];          \
      }                                                                         \
    }                                                                           \
  } while (0)

// One LSTM step for one WG slice (16 hidden units, all 4 gates; each wave
// covers 2 btiles). Inter-step ordering comes from kernel boundaries.
template<int H, int NWG, bool REV>
__device__ __forceinline__ void step_body(
    int t, const float* __restrict__ wihT, const int* __restrict__ idx,
    const __hip_bfloat16* __restrict__ whh,
    __hip_bfloat16* __restrict__ hist, float* __restrict__ cth,
    int wgl, char* ldsB)
{
  constexpr int NK = H / 32;
  constexpr int CPR = H / 8;
  const int tid = threadIdx.x;
  const int lane = tid & 63;
  const int wv = tid >> 6;
  const int l15 = lane & 15;
  const int kg = lane >> 4;
  const int col = wgl * 16 + l15;
  const int bt0 = wv * 2;
  const int aoff = l15 * 32 + kg * 8;
  const int kgc = (wgl & 1) * 2 + (l15 >> 3);
  const int jj = l15 & 7;
  const int kkw = wgl >> 1;

  // ---- stage Whh slice into LDS, fragment order (coalesced rows) ----
  for (int ch = tid; ch < 64 * CPR; ch += 256) {
    int r = ch / CPR, cb = ch % CPR;
    int g = r >> 4, c = r & 15;
    int kk = cb >> 2, kg2 = cb & 3;
    i32x4 v = *reinterpret_cast<const i32x4*>(
        reinterpret_cast<const char*>(whh) + ((size_t)(g * H + wgl * 16 + c) * H) * 2 + cb * 16);
    *reinterpret_cast<i32x4*>(ldsB + (((kk * 4 + g) * 64) + kg2 * 16 + c) * 16) = v;
  }

  // cell state from previous step (zero at t==0)
  float cst[2][4];
  if (t > 0) {
    f32x4 c0 = *reinterpret_cast<const f32x4*>(cth);
    f32x4 c1 = *reinterpret_cast<const f32x4*>(cth + 4);
    #pragma unroll
    for (int r = 0; r < 4; ++r) { cst[0][r] = c0[r]; cst[1][r] = c1[r]; }
  } else {
    #pragma unroll
    for (int i = 0; i < 2; ++i)
      #pragma unroll
      for (int r = 0; r < 4; ++r) cst[i][r] = 0.f;
  }

  float win[2][4][4];
  LOAD_WIN(win, t);

  __syncthreads();   // LDS B ready

  f32x4 acc[2][4];
  #pragma unroll
  for (int bt = 0; bt < 2; ++bt)
    #pragma unroll
    for (int g = 0; g < 4; ++g)
      #pragma unroll
      for (int r = 0; r < 4; ++r) acc[bt][g][r] = win[bt][r][g];

  if (t > 0) {
    // Burst A-loads (1KB contiguous per wave-load), vmcnt quarters so
    // LDS B-reads + MFMA overlap the remaining load returns. The win/cst
    // loads above are older than the A burst, so counted waits are safe.
    const __hip_bfloat16* hp = hist;
    const size_t tb = (size_t)(t - 1) * 8;
    i32x4 a[2][NK];
    #pragma unroll
    for (int kk = 0; kk < NK; ++kk) {
      a[0][kk] = load_g16(hp + ((tb + bt0) * NK + kk) * 512 + aoff);
      a[1][kk] = load_g16(hp + ((tb + bt0 + 1) * NK + kk) * 512 + aoff);
    }
    if constexpr (NK == 16) {
      VMWAIT(24); DO_QUARTER(0);
      VMWAIT(16); DO_QUARTER(4);
      VMWAIT(8);  DO_QUARTER(8);
      VMWAIT(0);  DO_QUARTER(12);
    } else {
      VMWAIT(12); DO_QUARTER(0);
      VMWAIT(8);  DO_QUARTER(2);
      VMWAIT(4);  DO_QUARTER(4);
      VMWAIT(0);  DO_QUARTER(6);
    }
  }

  // cell update; h -> scattered 2B stores into fragment-tiled history
  #pragma unroll
  for (int bt = 0; bt < 2; ++bt) {
    __hip_bfloat16* htile = hist + ((size_t)(t * 8 + bt0 + bt) * NK + kkw) * 512;
    #pragma unroll
    for (int r = 0; r < 4; ++r) {
      float gi = acc[bt][0][r], gf = acc[bt][1][r];
      float gg = acc[bt][2][r], go = acc[bt][3][r];
      float c = sigf(gf) * cst[bt][r] + sigf(gi) * tanhfast(gg);
      cst[bt][r] = c;
      int m = kg * 4 + r;
      htile[(m * 4 + kgc) * 8 + jj] = __float2bfloat16(sigf(go) * tanhfast(c));
    }
  }
  // persist cell state for the next step's kernel
  f32x4 c0, c1;
  #pragma unroll
  for (int r = 0; r < 4; ++r) { c0[r] = cst[0][r]; c1[r] = cst[1][r]; }
  *reinterpret_cast<f32x4*>(cth) = c0;
  *reinterpret_cast<f32x4*>(cth + 4) = c1;
}

__global__ __launch_bounds__(256, 1) void lstm_step(
    int t,
    const float* __restrict__ wihT_m, const float* __restrict__ wihT_pf,
    const float* __restrict__ wihT_pb,
    const int* __restrict__ src_idx,  const int* __restrict__ tgt_idx,
    const __hip_bfloat16* __restrict__ whh_pf_b, const __hip_bfloat16* __restrict__ whh_pb_b,
    const __hip_bfloat16* __restrict__ whh_m_b,
    __hip_bfloat16* __restrict__ hf, __hip_bfloat16* __restrict__ hb,
    __hip_bfloat16* __restrict__ hm,
    float* __restrict__ cstate)
{
  __shared__ __align__(16) char ldsB[65536];
  int wg = blockIdx.x;   // static role, no cross-WG communication at all
  float* cth = cstate + ((size_t)wg * 256 + threadIdx.x) * 8;
  if (wg < 32)
    step_body<HMOD, 32, false>(t, wihT_m, tgt_idx, whh_m_b, hm, cth, wg, ldsB);
  else if (wg < 48)
    step_body<HP, 16, false>(t, wihT_pf, src_idx, whh_pf_b, hf, cth, wg - 32, ldsB);
  else
    step_body<HP, 16, true>(t, wihT_pb, src_idx, whh_pb_b, hb, cth, wg - 48, ldsB);
}

__global__ __launch_bounds__(256, 1) void proj_kernel(
    const __hip_bfloat16* __restrict__ hf, const __hip_bfloat16* __restrict__ hb,
    const __hip_bfloat16* __restrict__ hm,
    const __hip_bfloat16* __restrict__ wsub_b, const __hip_bfloat16* __restrict__ wins_b,
    const float* __restrict__ b_sub, const float* __restrict__ b_ins,
    float* __restrict__ SPs, float* __restrict__ SPi,
    float* __restrict__ SMs, float* __restrict__ SMi)
{
  int wg = blockIdx.x;
  bool prior = wg < 64;
  int rowbase = (wg & 63) * 64;
  const int lane = threadIdx.x & 63;
  const int wv = threadIdx.x >> 6;
  const int l15 = lane & 15;
  const int kg = lane >> 4;
  const int frag = l15 * 32 + kg * 8;
  int arow = rowbase + wv * 16 + l15;
  int tt = arow >> 7;
  int bt = ((arow & 127) >> 4);

  f32x4 acc[2][4];
  #pragma unroll
  for (int i = 0; i < 2; ++i)
    #pragma unroll
    for (int ct = 0; ct < 4; ++ct) acc[i][ct] = (f32x4){0.f, 0.f, 0.f, 0.f};

  for (int kk = 0; kk < 16; ++kk) {
    int kb = kk * 32 + kg * 8;
    bf16x8 a;
    if (prior) {
      if (kk < 8) a = *reinterpret_cast<const bf16x8*>(hf + ((size_t)(tt * 8 + bt) * 8 + kk) * 512 + frag);
      else        a = *reinterpret_cast<const bf16x8*>(hb + ((size_t)((31 - tt) * 8 + bt) * 8 + (kk - 8)) * 512 + frag);
    } else {
      a = *reinterpret_cast<const bf16x8*>(hm + ((size_t)(tt * 8 + bt) * 16 + kk) * 512 + frag);
    }
    #pragma unroll
    for (int ct = 0; ct < 4; ++ct) {
      bf16x8 bs = *reinterpret_cast<const bf16x8*>(wsub_b + (size_t)(ct * 16 + l15) * HMOD + kb);
      bf16x8 bi = *reinterpret_cast<const bf16x8*>(wins_b + (size_t)(ct * 16 + l15) * HMOD + kb);
      acc[0][ct] = __builtin_amdgcn_mfma_f32_16x16x32_bf16(a, bs, acc[0][ct], 0, 0, 0);
      acc[1][ct] = __builtin_amdgcn_mfma_f32_16x16x32_bf16(a, bi, acc[1][ct], 0, 0, 0);
    }
  }
  #pragma unroll
  for (int ct = 0; ct < 4; ++ct) {
    int colo = ct * 16 + l15;
    #pragma unroll
    for (int r = 0; r < 4; ++r) {
      int row = rowbase + wv * 16 + kg * 4 + r;
      if (prior) {
        SPs[(size_t)row * 64 + colo] = acc[0][ct][r] + (colo < OUTV ? b_sub[colo] : 0.f);
        SPi[(size_t)row * 64 + colo] = acc[1][ct][r] + (colo < OUTV ? b_ins[colo] : 0.f);
      } else {
        SMs[(size_t)row * 64 + colo] = acc[0][ct][r];
        SMi[(size_t)row * 64 + colo] = acc[1][ct][r];
      }
    }
  }
}

__global__ __launch_bounds__(256, 1) void out_kernel(
    const float* __restrict__ SPs, const float* __restrict__ SPi,
    const float* __restrict__ SMs, const float* __restrict__ SMi,
    const int* __restrict__ tgt_idx, float* __restrict__ out)
{
  int b = blockIdx.x;
  __shared__ float sps[32][66], spi[32][66], sms[32][66], smi[32][66];
  __shared__ int tg[32];
  for (int i = threadIdx.x; i < 32 * 64; i += 256) {
    int p = i >> 6, o = i & 63;
    size_t base = ((size_t)p * BATCH + b) * 64 + o;
    sps[p][o] = SPs[base]; spi[p][o] = SPi[base];
    sms[p][o] = SMs[base]; smi[p][o] = SMi[base];
  }
  if (threadIdx.x < 32) tg[threadIdx.x] = tgt_idx[threadIdx.x * BATCH + b];
  __syncthreads();

  for (int pr = threadIdx.x; pr < PLEN * MLEN; pr += 256) {
    int p = pr >> 5, m = pr & 31;
    float mxs = -1e30f, mxi = -1e30f;
    for (int o = 0; o < OUTV; ++o) {
      mxs = fmaxf(mxs, sps[p][o] + sms[m][o]);
      mxi = fmaxf(mxi, spi[p][o] + smi[m][o]);
    }
    float ss = 0.f, si = 0.f;
    for (int o = 0; o < OUTV; ++o) {
      ss += __expf(sps[p][o] + sms[m][o] - mxs);
      si += __expf(spi[p][o] + smi[m][o] - mxi);
    }
    float lses = mxs + __logf(ss);
    float lsei = mxi + __logf(si);
    size_t pm = (size_t)(p * MLEN + m) * BATCH + b;
    out[pm] = sps[p][52] + sms[m][52] - lses;
    out[OFF_END + pm] = spi[p][52] + smi[m][52] - lsei;
    if (m < 31) {
      int ttg = tg[m + 1];
      size_t pms = (size_t)(p * 31 + m) * BATCH + b;
      out[OFF_SUB + pms] = sps[p][ttg] + sms[m][ttg] - lses;
      out[OFF_INS + pms] = spi[p][ttg] + smi[m][ttg] - lsei;
    }
  }
}

extern "C" void kernel_launch(void* const* d_in, const int* in_sizes, int n_in,
                              void* d_out, int out_size, void* d_ws, size_t ws_size,
                              hipStream_t stream) {
  const float* src_oh = (const float*)d_in[0];
  const float* Wih_pf = (const float*)d_in[2];
  const float* Whh_pf = (const float*)d_in[3];
  const float* b_pf   = (const float*)d_in[4];
  const float* Wih_pb = (const float*)d_in[5];
  const float* Whh_pb = (const float*)d_in[6];
  const float* b_pb   = (const float*)d_in[7];
  const float* Wih_m  = (const float*)d_in[8];
  const float* Whh_m  = (const float*)d_in[9];
  const float* b_m    = (const float*)d_in[10];
  const float* W_sub  = (const float*)d_in[11];
  const float* b_sub  = (const float*)d_in[12];
  const float* W_ins  = (const float*)d_in[13];
  const float* b_ins  = (const float*)d_in[14];
  const int*   tgt    = (const int*)d_in[15];

  char* ws = (char*)d_ws;
  int* src_idx = (int*)(ws + WS_SRCIDX);
  __hip_bfloat16* whh_pf_b = (__hip_bfloat16*)(ws + WS_WHH_PF);
  __hip_bfloat16* whh_pb_b = (__hip_bfloat16*)(ws + WS_WHH_PB);
  __hip_bfloat16* whh_m_b  = (__hip_bfloat16*)(ws + WS_WHH_M);
  __hip_bfloat16* wsub_b   = (__hip_bfloat16*)(ws + WS_WSUB);
  __hip_bfloat16* wins_b   = (__hip_bfloat16*)(ws + WS_WINS);
  __hip_bfloat16* hf = (__hip_bfloat16*)(ws + WS_HF);
  __hip_bfloat16* hb = (__hip_bfloat16*)(ws + WS_HB);
  __hip_bfloat16* hm = (__hip_bfloat16*)(ws + WS_HM);
  float* wihT_m  = (float*)(ws + WS_WIHT_M);
  float* wihT_pf = (float*)(ws + WS_WIHT_PF);
  float* wihT_pb = (float*)(ws + WS_WIHT_PB);
  float* cstate  = (float*)(ws + WS_CST);
  float* SPs = (float*)(ws + WS_SPS);
  float* SPi = (float*)(ws + WS_SPI);
  float* SMs = (float*)(ws + WS_SMS);
  float* SMi = (float*)(ws + WS_SMI);

  prep_kernel<<<256, 256, 0, stream>>>(Whh_pf, Whh_pb, Whh_m, W_sub, W_ins, src_oh,
                                       Wih_pf, b_pf, Wih_pb, b_pb, Wih_m, b_m,
                                       whh_pf_b, whh_pb_b, whh_m_b, wsub_b, wins_b,
                                       wihT_m, wihT_pf, wihT_pb, src_idx);
  for (int t = 0; t < 32; ++t)
    lstm_step<<<64, 256, 0, stream>>>(t, wihT_m, wihT_pf, wihT_pb, src_idx, tgt,
                                      whh_pf_b, whh_pb_b, whh_m_b,
                                      hf, hb, hm, cstate);
  proj_kernel<<<128, 256, 0, stream>>>(hf, hb, hm, wsub_b, wins_b, b_sub, b_ins,
                                       SPs, SPi, SMs, SMi);
  out_kernel<<<128, 256, 0, stream>>>(SPs, SPi, SMs, SMi, tgt, (float*)d_out);
}

// Round 14
// 282.490 us; speedup vs baseline: 1.2633x; 1.2633x over previous
//
#include <hip/hip_runtime.h>
#include <hip/hip_bf16.h>

// EditModel: bidi prior LSTM (H=256) + modern LSTM (H=512) + factored
// logit heads. ctx@W^T = prior@W^T (+) modern@W^T so no [P,M,B,2H] tensor.
//
// R14 = R13's PROVEN kernel-per-step structure (no inter-block sync at all;
// kernel boundaries provide ordering/coherence) with three in-skeleton
// optimizations: (1) A-burst issued BEFORE B staging so cross-XCD h-load
// latency hides under the stage (syncthreads drains everything; no counted
// vmcnt needed); (2) 128 WGs -- batch split 2x: 1 btile/wave, half the A
// traffic, MFMA and LDS reads per WG, 128 CUs busy; (3) t=0 skips B-stage.
// Data path: fragment-tiled h (1KB contiguous A bursts), LDS-B fragment
// order, wihT bias-folded coalesced gather. c state via global (SMi alias).

#define PLEN 32
#define MLEN 32
#define BATCH 128
#define HP 256
#define HMOD 512
#define DIN 54
#define OUTV 53

typedef __bf16 bf16x8 __attribute__((ext_vector_type(8)));
typedef float f32x4 __attribute__((ext_vector_type(4)));
typedef int i32x4 __attribute__((ext_vector_type(4)));

// ---- workspace layout (bytes) ----
#define WS_SRCIDX   1024
#define WS_WHH_PF   17408
#define WS_WHH_PB   541696
#define WS_WHH_M    1065984
#define WS_WSUB     3163136
#define WS_WINS     3228672
#define WS_HF       3294208
#define WS_HB       5391360
#define WS_HM       7488512
#define WS_SPS      11682816   // 4096*64 f32
#define WS_SPI      12731392
#define WS_SMS      13779968
#define WS_SMI      14828544   // ends 15877120
// Aliases (regions dead during the LSTM phase):
#define WS_WIHT_M   WS_SPS     // 54*2048 f32 = 442368 B
#define WS_WIHT_PF  WS_SPI     // 54*1024 f32
#define WS_WIHT_PB  WS_SMS     // 54*1024 f32
#define WS_CST      WS_SMI     // 128*256*4 f32 = 524288 B <= 1MB region

#define OFF_END 131072
#define OFF_SUB 262144
#define OFF_INS 389120

__device__ __forceinline__ float sigf(float x) { return 1.0f / (1.0f + __expf(-x)); }
__device__ __forceinline__ float tanhfast(float x) {
  x = fminf(15.0f, fmaxf(-15.0f, x));
  float e = __expf(2.0f * x);
  return (e - 1.0f) / (e + 1.0f);
}

__device__ __forceinline__ i32x4 load_g16(const void* p) {
  i32x4 r;
  asm volatile("global_load_dwordx4 %0, %1, off" : "=v"(r) : "v"(p) : "memory");
  return r;
}

__global__ void prep_kernel(const float* __restrict__ Whh_pf, const float* __restrict__ Whh_pb,
                            const float* __restrict__ Whh_m,
                            const float* __restrict__ W_sub, const float* __restrict__ W_ins,
                            const float* __restrict__ src_oh,
                            const float* __restrict__ Wih_pf, const float* __restrict__ b_pf,
                            const float* __restrict__ Wih_pb, const float* __restrict__ b_pb,
                            const float* __restrict__ Wih_m,  const float* __restrict__ b_m,
                            __hip_bfloat16* __restrict__ whh_pf_b, __hip_bfloat16* __restrict__ whh_pb_b,
                            __hip_bfloat16* __restrict__ whh_m_b,
                            __hip_bfloat16* __restrict__ wsub_b, __hip_bfloat16* __restrict__ wins_b,
                            float* __restrict__ wihT_m, float* __restrict__ wihT_pf,
                            float* __restrict__ wihT_pb,
                            int* __restrict__ src_idx)
{
  int tid = blockIdx.x * blockDim.x + threadIdx.x;
  int stride = gridDim.x * blockDim.x;
  for (int k = tid; k < 4 * HP * HP; k += stride) {
    whh_pf_b[k] = __float2bfloat16(Whh_pf[k]);
    whh_pb_b[k] = __float2bfloat16(Whh_pb[k]);
  }
  for (int k = tid; k < 4 * HMOD * HMOD; k += stride)
    whh_m_b[k] = __float2bfloat16(Whh_m[k]);
  for (int k = tid; k < 64 * HMOD; k += stride) {
    int r = k >> 9, c = k & 511;
    wsub_b[k] = __float2bfloat16(r < OUTV ? W_sub[r * HMOD + c] : 0.0f);
    wins_b[k] = __float2bfloat16(r < OUTV ? W_ins[r * HMOD + c] : 0.0f);
  }
  // transposed input-proj weights, bias folded: wihT[ii][c] = Wih[c][ii]+b[c]
  for (int j = tid; j < DIN * 4 * HMOD; j += stride) {
    int ii = j >> 11, c = j & 2047;
    wihT_m[j] = Wih_m[(size_t)c * DIN + ii] + b_m[c];
  }
  for (int j = tid; j < DIN * 4 * HP; j += stride) {
    int ii = j >> 10, c = j & 1023;
    wihT_pf[j] = Wih_pf[(size_t)c * DIN + ii] + b_pf[c];
    wihT_pb[j] = Wih_pb[(size_t)c * DIN + ii] + b_pb[c];
  }
  for (int k = tid; k < PLEN * BATCH; k += stride) {
    const float* row = src_oh + (size_t)k * DIN;
    int idx = 0;
    for (int j = 0; j < DIN; ++j) if (row[j] > 0.5f) idx = j;
    src_idx[k] = idx;
  }
}

// h history layout, per LSTM (NK = H/32 k-blocks):
//   tile(t, btile, kk) = 512 bf16 (1KB) at ((t*8 + btile)*NK + kk)*512
//   elem within tile: (m*4 + kgc)*8 + j, m = b&15, k = kk*32 + kgc*8 + j.
// A wave's MFMA A-fragment load covers one full tile contiguously.

// One LSTM step for one WG slice: 16 hidden cols (colgroup wgl), 64 batch
// rows (half) -- 1 btile per wave. Inter-step ordering: kernel boundaries.
template<int H, bool REV>
__device__ __forceinline__ void step_body(
    int t, const float* __restrict__ wihT, const int* __restrict__ idx,
    const __hip_bfloat16* __restrict__ whh,
    __hip_bfloat16* __restrict__ hist, float* __restrict__ cth,
    int wgl, int half, char* ldsB)
{
  constexpr int NK = H / 32;
  constexpr int CPR = H / 8;
  const int tid = threadIdx.x;
  const int lane = tid & 63;
  const int wv = tid >> 6;
  const int l15 = lane & 15;
  const int kg = lane >> 4;
  const int col = wgl * 16 + l15;
  const int btile = half * 4 + wv;
  const int aoff = l15 * 32 + kg * 8;
  const int kgc = (wgl & 1) * 2 + (l15 >> 3);
  const int jj = l15 & 7;
  const int kkw = wgl >> 1;

  // ---- 1) A-burst FIRST: cross-XCD h loads start draining immediately ----
  i32x4 a[NK];
  if (t > 0) {
    const size_t tb = (size_t)(t - 1) * 8;
    #pragma unroll
    for (int kk = 0; kk < NK; ++kk)
      a[kk] = load_g16(hist + ((tb + btile) * NK + kk) * 512 + aoff);
  }

  // ---- 2) overlap: input-proj gather + cell state + B staging ----
  float win[4][4];
  {
    int tin_ = REV ? (31 - t) : t;
    #pragma unroll
    for (int r = 0; r < 4; ++r) {
      int b_ = btile * 16 + kg * 4 + r;
      int ii_ = idx[tin_ * BATCH + b_];
      const float* row_ = wihT + (size_t)ii_ * (4 * H);
      #pragma unroll
      for (int g = 0; g < 4; ++g) win[r][g] = row_[g * H + col];
    }
  }

  float cst[4];
  if (t > 0) {
    f32x4 c0 = *reinterpret_cast<const f32x4*>(cth);
    #pragma unroll
    for (int r = 0; r < 4; ++r) cst[r] = c0[r];
  } else {
    #pragma unroll
    for (int r = 0; r < 4; ++r) cst[r] = 0.f;
  }

  f32x4 acc[4];
  #pragma unroll
  for (int g = 0; g < 4; ++g)
    #pragma unroll
    for (int r = 0; r < 4; ++r) acc[g][r] = win[r][g];

  if (t > 0) {
    // stage Whh slice into LDS, fragment order (coalesced row reads)
    for (int ch = tid; ch < 64 * CPR; ch += 256) {
      int r = ch / CPR, cb = ch % CPR;
      int g = r >> 4, c = r & 15;
      int kk = cb >> 2, kg2 = cb & 3;
      i32x4 v = *reinterpret_cast<const i32x4*>(
          reinterpret_cast<const char*>(whh) + ((size_t)(g * H + wgl * 16 + c) * H) * 2 + cb * 16);
      *reinterpret_cast<i32x4*>(ldsB + (((kk * 4 + g) * 64) + kg2 * 16 + c) * 16) = v;
    }
    __syncthreads();   // drains A-burst (vmcnt) + LDS writes (lgkmcnt)

    // ---- 3) MFMA: LDS B fragments x in-reg A fragments ----
    #pragma unroll
    for (int kk = 0; kk < NK; ++kk) {
      bf16x8 a0 = __builtin_bit_cast(bf16x8, a[kk]);
      #pragma unroll
      for (int g = 0; g < 4; ++g) {
        bf16x8 bfr = *reinterpret_cast<const bf16x8*>(
            ldsB + (((kk * 4 + g) * 64) + lane) * 16);
        acc[g] = __builtin_amdgcn_mfma_f32_16x16x32_bf16(a0, bfr, acc[g], 0, 0, 0);
      }
    }
  }

  // ---- 4) cell update; h -> fragment-tiled history; persist c ----
  __hip_bfloat16* htile = hist + ((size_t)(t * 8 + btile) * NK + kkw) * 512;
  f32x4 cout;
  #pragma unroll
  for (int r = 0; r < 4; ++r) {
    float gi = acc[0][r], gf = acc[1][r], gg = acc[2][r], go = acc[3][r];
    float c = sigf(gf) * cst[r] + sigf(gi) * tanhfast(gg);
    cout[r] = c;
    int m = kg * 4 + r;
    htile[(m * 4 + kgc) * 8 + jj] = __float2bfloat16(sigf(go) * tanhfast(c));
  }
  *reinterpret_cast<f32x4*>(cth) = cout;
}

__global__ __launch_bounds__(256, 1) void lstm_step(
    int t,
    const float* __restrict__ wihT_m, const float* __restrict__ wihT_pf,
    const float* __restrict__ wihT_pb,
    const int* __restrict__ src_idx,  const int* __restrict__ tgt_idx,
    const __hip_bfloat16* __restrict__ whh_pf_b, const __hip_bfloat16* __restrict__ whh_pb_b,
    const __hip_bfloat16* __restrict__ whh_m_b,
    __hip_bfloat16* __restrict__ hf, __hip_bfloat16* __restrict__ hb,
    __hip_bfloat16* __restrict__ hm,
    float* __restrict__ cstate)
{
  __shared__ __align__(16) char ldsB[65536];
  int wg = blockIdx.x;   // static roles: [0,64) modern, [64,96) pf, [96,128) pb
  float* cth = cstate + ((size_t)wg * 256 + threadIdx.x) * 4;
  if (wg < 64)
    step_body<HMOD, false>(t, wihT_m, tgt_idx, whh_m_b, hm, cth, wg >> 1, wg & 1, ldsB);
  else if (wg < 96)
    step_body<HP, false>(t, wihT_pf, src_idx, whh_pf_b, hf, cth, (wg - 64) >> 1, (wg - 64) & 1, ldsB);
  else
    step_body<HP, true>(t, wihT_pb, src_idx, whh_pb_b, hb, cth, (wg - 96) >> 1, (wg - 96) & 1, ldsB);
}

__global__ __launch_bounds__(256, 1) void proj_kernel(
    const __hip_bfloat16* __restrict__ hf, const __hip_bfloat16* __restrict__ hb,
    const __hip_bfloat16* __restrict__ hm,
    const __hip_bfloat16* __restrict__ wsub_b, const __hip_bfloat16* __restrict__ wins_b,
    const float* __restrict__ b_sub, const float* __restrict__ b_ins,
    float* __restrict__ SPs, float* __restrict__ SPi,
    float* __restrict__ SMs, float* __restrict__ SMi)
{
  int wg = blockIdx.x;
  bool prior = wg < 64;
  int rowbase = (wg & 63) * 64;
  const int lane = threadIdx.x & 63;
  const int wv = threadIdx.x >> 6;
  const int l15 = lane & 15;
  const int kg = lane >> 4;
  const int frag = l15 * 32 + kg * 8;
  int arow = rowbase + wv * 16 + l15;
  int tt = arow >> 7;
  int bt = ((arow & 127) >> 4);

  f32x4 acc[2][4];
  #pragma unroll
  for (int i = 0; i < 2; ++i)
    #pragma unroll
    for (int ct = 0; ct < 4; ++ct) acc[i][ct] = (f32x4){0.f, 0.f, 0.f, 0.f};

  for (int kk = 0; kk < 16; ++kk) {
    int kb = kk * 32 + kg * 8;
    bf16x8 a;
    if (prior) {
      if (kk < 8) a = *reinterpret_cast<const bf16x8*>(hf + ((size_t)(tt * 8 + bt) * 8 + kk) * 512 + frag);
      else        a = *reinterpret_cast<const bf16x8*>(hb + ((size_t)((31 - tt) * 8 + bt) * 8 + (kk - 8)) * 512 + frag);
    } else {
      a = *reinterpret_cast<const bf16x8*>(hm + ((size_t)(tt * 8 + bt) * 16 + kk) * 512 + frag);
    }
    #pragma unroll
    for (int ct = 0; ct < 4; ++ct) {
      bf16x8 bs = *reinterpret_cast<const bf16x8*>(wsub_b + (size_t)(ct * 16 + l15) * HMOD + kb);
      bf16x8 bi = *reinterpret_cast<const bf16x8*>(wins_b + (size_t)(ct * 16 + l15) * HMOD + kb);
      acc[0][ct] = __builtin_amdgcn_mfma_f32_16x16x32_bf16(a, bs, acc[0][ct], 0, 0, 0);
      acc[1][ct] = __builtin_amdgcn_mfma_f32_16x16x32_bf16(a, bi, acc[1][ct], 0, 0, 0);
    }
  }
  #pragma unroll
  for (int ct = 0; ct < 4; ++ct) {
    int colo = ct * 16 + l15;
    #pragma unroll
    for (int r = 0; r < 4; ++r) {
      int row = rowbase + wv * 16 + kg * 4 + r;
      if (prior) {
        SPs[(size_t)row * 64 + colo] = acc[0][ct][r] + (colo < OUTV ? b_sub[colo] : 0.f);
        SPi[(size_t)row * 64 + colo] = acc[1][ct][r] + (colo < OUTV ? b_ins[colo] : 0.f);
      } else {
        SMs[(size_t)row * 64 + colo] = acc[0][ct][r];
        SMi[(size_t)row * 64 + colo] = acc[1][ct][r];
      }
    }
  }
}

__global__ __launch_bounds__(256, 1) void out_kernel(
    const float* __restrict__ SPs, const float* __restrict__ SPi,
    const float* __restrict__ SMs, const float* __restrict__ SMi,
    const int* __restrict__ tgt_idx, float* __restrict__ out)
{
  int b = blockIdx.x;
  __shared__ float sps[32][66], spi[32][66], sms[32][66], smi[32][66];
  __shared__ int tg[32];
  for (int i = threadIdx.x; i < 32 * 64; i += 256) {
    int p = i >> 6, o = i & 63;
    size_t base = ((size_t)p * BATCH + b) * 64 + o;
    sps[p][o] = SPs[base]; spi[p][o] = SPi[base];
    sms[p][o] = SMs[base]; smi[p][o] = SMi[base];
  }
  if (threadIdx.x < 32) tg[threadIdx.x] = tgt_idx[threadIdx.x * BATCH + b];
  __syncthreads();

  for (int pr = threadIdx.x; pr < PLEN * MLEN; pr += 256) {
    int p = pr >> 5, m = pr & 31;
    float mxs = -1e30f, mxi = -1e30f;
    for (int o = 0; o < OUTV; ++o) {
      mxs = fmaxf(mxs, sps[p][o] + sms[m][o]);
      mxi = fmaxf(mxi, spi[p][o] + smi[m][o]);
    }
    float ss = 0.f, si = 0.f;
    for (int o = 0; o < OUTV; ++o) {
      ss += __expf(sps[p][o] + sms[m][o] - mxs);
      si += __expf(spi[p][o] + smi[m][o] - mxi);
    }
    float lses = mxs + __logf(ss);
    float lsei = mxi + __logf(si);
    size_t pm = (size_t)(p * MLEN + m) * BATCH + b;
    out[pm] = sps[p][52] + sms[m][52] - lses;
    out[OFF_END + pm] = spi[p][52] + smi[m][52] - lsei;
    if (m < 31) {
      int ttg = tg[m + 1];
      size_t pms = (size_t)(p * 31 + m) * BATCH + b;
      out[OFF_SUB + pms] = sps[p][ttg] + sms[m][ttg] - lses;
      out[OFF_INS + pms] = spi[p][ttg] + smi[m][ttg] - lsei;
    }
  }
}

extern "C" void kernel_launch(void* const* d_in, const int* in_sizes, int n_in,
                              void* d_out, int out_size, void* d_ws, size_t ws_size,
                              hipStream_t stream) {
  const float* src_oh = (const float*)d_in[0];
  const float* Wih_pf = (const float*)d_in[2];
  const float* Whh_pf = (const float*)d_in[3];
  const float* b_pf   = (const float*)d_in[4];
  const float* Wih_pb = (const float*)d_in[5];
  const float* Whh_pb = (const float*)d_in[6];
  const float* b_pb   = (const float*)d_in[7];
  const float* Wih_m  = (const float*)d_in[8];
  const float* Whh_m  = (const float*)d_in[9];
  const float* b_m    = (const float*)d_in[10];
  const float* W_sub  = (const float*)d_in[11];
  const float* b_sub  = (const float*)d_in[12];
  const float* W_ins  = (const float*)d_in[13];
  const float* b_ins  = (const float*)d_in[14];
  const int*   tgt    = (const int*)d_in[15];

  char* ws = (char*)d_ws;
  int* src_idx = (int*)(ws + WS_SRCIDX);
  __hip_bfloat16* whh_pf_b = (__hip_bfloat16*)(ws + WS_WHH_PF);
  __hip_bfloat16* whh_pb_b = (__hip_bfloat16*)(ws + WS_WHH_PB);
  __hip_bfloat16* whh_m_b  = (__hip_bfloat16*)(ws + WS_WHH_M);
  __hip_bfloat16* wsub_b   = (__hip_bfloat16*)(ws + WS_WSUB);
  __hip_bfloat16* wins_b   = (__hip_bfloat16*)(ws + WS_WINS);
  __hip_bfloat16* hf = (__hip_bfloat16*)(ws + WS_HF);
  __hip_bfloat16* hb = (__hip_bfloat16*)(ws + WS_HB);
  __hip_bfloat16* hm = (__hip_bfloat16*)(ws + WS_HM);
  float* wihT_m  = (float*)(ws + WS_WIHT_M);
  float* wihT_pf = (float*)(ws + WS_WIHT_PF);
  float* wihT_pb = (float*)(ws + WS_WIHT_PB);
  float* cstate  = (float*)(ws + WS_CST);
  float* SPs = (float*)(ws + WS_SPS);
  float* SPi = (float*)(ws + WS_SPI);
  float* SMs = (float*)(ws + WS_SMS);
  float* SMi = (float*)(ws + WS_SMI);

  prep_kernel<<<256, 256, 0, stream>>>(Whh_pf, Whh_pb, Whh_m, W_sub, W_ins, src_oh,
                                       Wih_pf, b_pf, Wih_pb, b_pb, Wih_m, b_m,
                                       whh_pf_b, whh_pb_b, whh_m_b, wsub_b, wins_b,
                                       wihT_m, wihT_pf, wihT_pb, src_idx);
  for (int t = 0; t < 32; ++t)
    lstm_step<<<128, 256, 0, stream>>>(t, wihT_m, wihT_pf, wihT_pb, src_idx, tgt,
                                       whh_pf_b, whh_pb_b, whh_m_b,
                                       hf, hb, hm, cstate);
  proj_kernel<<<128, 256, 0, stream>>>(hf, hb, hm, wsub_b, wins_b, b_sub, b_ins,
                                       SPs, SPi, SMs, SMi);
  out_kernel<<<128, 256, 0, stream>>>(SPs, SPi, SMs, SMi, tgt, (float*)d_out);
}